// Round 1
// baseline (3061.221 us; speedup 1.0000x reference)
//
#include <hip/hip_runtime.h>
#include <cstdint>
#include <cstddef>

#define B_    256
#define T_    128
#define SIG_  64
#define MET_  32
#define H_    256
#define F_    16
#define NCOL  1040   // [i:0..255 | ste:256..511 | fre:512..527 | c:528..783 | o:784..1039]
#define TC    16
#define NCHUNK (T_/TC)

__device__ __forceinline__ float hsig(float x) {
    return fminf(fmaxf(x * (1.0f/6.0f) + 0.5f, 0.0f), 1.0f);
}

__device__ __forceinline__ unsigned short f2bf(float f) {
    unsigned int u = __float_as_uint(f);
    unsigned int r = (u + 0x7fffu + ((u >> 16) & 1u)) >> 16;
    return (unsigned short)r;
}

__device__ __forceinline__ void colmap(int n, int& sec, int& idx) {
    if (n < 256)      { sec = 0; idx = n; }
    else if (n < 512) { sec = 1; idx = n - 256; }
    else if (n < 528) { sec = 2; idx = n - 512; }
    else if (n < 784) { sec = 3; idx = n - 528; }
    else              { sec = 4; idx = n - 784; }
}

// ---------------------------------------------------------------------------
// Pack weights: Wcat[96][1040] f32, bcat[1040] f32, UT[1040][256] bf16 (U^T)
// ---------------------------------------------------------------------------
__global__ __launch_bounds__(256) void pack_kernel(
    const float* __restrict__ Wis, const float* __restrict__ Wstes, const float* __restrict__ Wfres,
    const float* __restrict__ Wcs, const float* __restrict__ Wos,
    const float* __restrict__ Wim, const float* __restrict__ Wstem, const float* __restrict__ Wfrem,
    const float* __restrict__ Wcm, const float* __restrict__ Wom,
    const float* __restrict__ Ui, const float* __restrict__ Uste, const float* __restrict__ Ufre,
    const float* __restrict__ Uc, const float* __restrict__ Uo,
    const float* __restrict__ bi, const float* __restrict__ bste, const float* __restrict__ bfre,
    const float* __restrict__ bc, const float* __restrict__ bo,
    float* __restrict__ Wcat, float* __restrict__ bcat, unsigned short* __restrict__ UT)
{
    int gtid = blockIdx.x * blockDim.x + threadIdx.x;
    int stride = gridDim.x * blockDim.x;
    const float* Wsig[5] = {Wis, Wstes, Wfres, Wcs, Wos};
    const float* Wmet[5] = {Wim, Wstem, Wfrem, Wcm, Wom};
    const float* Us[5]   = {Ui, Uste, Ufre, Uc, Uo};
    const float* bs[5]   = {bi, bste, bfre, bc, bo};

    for (int i = gtid; i < 96*NCOL; i += stride) {
        int k = i / NCOL, n = i - k*NCOL;
        int sec, idx; colmap(n, sec, idx);
        int secN = (sec == 2) ? F_ : H_;
        float v = (k < 64) ? Wsig[sec][k*secN + idx] : Wmet[sec][(k-64)*secN + idx];
        Wcat[k*NCOL + n] = v;
    }
    for (int n = gtid; n < NCOL; n += stride) {
        int sec, idx; colmap(n, sec, idx);
        bcat[n] = bs[sec][idx];
    }
    for (int i = gtid; i < NCOL*H_; i += stride) {
        int n = i >> 8, k = i & 255;
        int sec, idx; colmap(n, sec, idx);
        int secN = (sec == 2) ? F_ : H_;
        UT[n*H_ + k] = f2bf(Us[sec][k*secN + idx]);
    }
}

// ---------------------------------------------------------------------------
// Phase 1: input projection GEMM for one time chunk.
// X[m][n] = sum_k A[m][k] * Wcat[k][n] + bcat[n],  m = b*TC + tl (4096 rows)
// A[m][k] = signal[b, t0+tl, k] (k<64) else metmast[b, t0+tl, k-64]
// 128x128 tile, 8x8 micro-tile, KTILE=32 (3 k-tiles).
// ---------------------------------------------------------------------------
__global__ __launch_bounds__(256) void proj_kernel(
    const float* __restrict__ sig, const float* __restrict__ met,
    const float* __restrict__ Wcat, const float* __restrict__ bcat,
    float* __restrict__ X, int t0)
{
    __shared__ float A_s[32][128];
    __shared__ float W_s[32][128];
    int tid = threadIdx.x;
    int c0b = blockIdx.x * 128;
    int m0  = blockIdx.y * 128;
    int r0  = (tid >> 4) * 8;
    int c0t = (tid & 15) * 8;

    float acc[8][8];
    #pragma unroll
    for (int i = 0; i < 8; ++i)
        #pragma unroll
        for (int j = 0; j < 8; ++j) acc[i][j] = 0.0f;

    for (int k0 = 0; k0 < 96; k0 += 32) {
        for (int idx = tid; idx < 32*128; idx += 256) {
            int ml = idx & 127, kk = idx >> 7;
            int m = m0 + ml;
            int b = m >> 4, tl = m & 15;
            int g = b * T_ + t0 + tl;
            int k = k0 + kk;
            float v = (k < 64) ? sig[g*SIG_ + k] : met[g*MET_ + (k - 64)];
            A_s[kk][ml] = v;
        }
        for (int idx = tid; idx < 32*128; idx += 256) {
            int c = idx & 127, kk = idx >> 7;
            int n = c0b + c;
            W_s[kk][c] = (n < NCOL) ? Wcat[(k0+kk)*NCOL + n] : 0.0f;
        }
        __syncthreads();
        #pragma unroll
        for (int kk = 0; kk < 32; ++kk) {
            float4 a0 = *(const float4*)&A_s[kk][r0];
            float4 a1 = *(const float4*)&A_s[kk][r0+4];
            float4 w0 = *(const float4*)&W_s[kk][c0t];
            float4 w1 = *(const float4*)&W_s[kk][c0t+4];
            float av[8] = {a0.x,a0.y,a0.z,a0.w,a1.x,a1.y,a1.z,a1.w};
            float wv[8] = {w0.x,w0.y,w0.z,w0.w,w1.x,w1.y,w1.z,w1.w};
            #pragma unroll
            for (int i = 0; i < 8; ++i)
                #pragma unroll
                for (int j = 0; j < 8; ++j)
                    acc[i][j] = fmaf(av[i], wv[j], acc[i][j]);
        }
        __syncthreads();
    }
    #pragma unroll
    for (int i = 0; i < 8; ++i) {
        int m = m0 + r0 + i;
        #pragma unroll
        for (int j = 0; j < 8; ++j) {
            int n = c0b + c0t + j;
            if (n < NCOL) X[(size_t)m*NCOL + n] = acc[i][j] + bcat[n];
        }
    }
}

// ---------------------------------------------------------------------------
// Phase 2: recurrence over one chunk of TC steps. One block per batch element.
// Thread t owns h-index t: S_re[16], S_im[16] in registers; h in LDS.
// ---------------------------------------------------------------------------
__device__ __forceinline__ float dot8(uint4 u, float4 ha, float4 hb, float acc) {
    acc = fmaf(__uint_as_float(u.x << 16),          ha.x, acc);
    acc = fmaf(__uint_as_float(u.x & 0xffff0000u),  ha.y, acc);
    acc = fmaf(__uint_as_float(u.y << 16),          ha.z, acc);
    acc = fmaf(__uint_as_float(u.y & 0xffff0000u),  ha.w, acc);
    acc = fmaf(__uint_as_float(u.z << 16),          hb.x, acc);
    acc = fmaf(__uint_as_float(u.z & 0xffff0000u),  hb.y, acc);
    acc = fmaf(__uint_as_float(u.w << 16),          hb.z, acc);
    acc = fmaf(__uint_as_float(u.w & 0xffff0000u),  hb.w, acc);
    return acc;
}

__global__ __launch_bounds__(256) void recur_kernel(
    const float* __restrict__ X, const unsigned short* __restrict__ UT,
    float* __restrict__ h_g, float* __restrict__ Sre_g, float* __restrict__ Sim_g,
    const float* __restrict__ U_a, const float* __restrict__ b_a,
    const float* __restrict__ W_p, const float* __restrict__ b_p,
    const float* __restrict__ fc_w, const float* __restrict__ fc_b,
    float* __restrict__ out, int t0)
{
    __shared__ float h_s[H_];
    __shared__ float pre_s[NCOL];
    __shared__ float cs[16], sn[16], ua_s[16];

    int tid = threadIdx.x;
    int b = blockIdx.x;

    float Sre[16], Sim[16];
    if (t0 == 0) {
        h_s[tid] = 0.0f;
        #pragma unroll
        for (int f = 0; f < 16; ++f) { Sre[f] = 0.0f; Sim[f] = 0.0f; }
    } else {
        h_s[tid] = h_g[b*H_ + tid];
        const float4* pr = (const float4*)(Sre_g + ((size_t)b*H_ + tid)*16);
        const float4* pi = (const float4*)(Sim_g + ((size_t)b*H_ + tid)*16);
        #pragma unroll
        for (int q = 0; q < 4; ++q) {
            float4 r = pr[q], im = pi[q];
            Sre[q*4+0]=r.x; Sre[q*4+1]=r.y; Sre[q*4+2]=r.z; Sre[q*4+3]=r.w;
            Sim[q*4+0]=im.x; Sim[q*4+1]=im.y; Sim[q*4+2]=im.z; Sim[q*4+3]=im.w;
        }
    }
    if (tid < 16) {
        float ang = (float)tid * 0.39269908169872414f; // 2*pi/16
        cs[tid] = cosf(ang);
        sn[tid] = sinf(ang);
        ua_s[tid] = U_a[tid];
    }
    float ba = b_a[tid];
    __syncthreads();

    int col4 = 1024 + (tid & 15);
    const uint4* U0 = (const uint4*)(UT + (size_t)(tid      ) * H_);
    const uint4* U1 = (const uint4*)(UT + (size_t)(tid + 256) * H_);
    const uint4* U2 = (const uint4*)(UT + (size_t)(tid + 512) * H_);
    const uint4* U3 = (const uint4*)(UT + (size_t)(tid + 768) * H_);
    const uint4* U4 = (const uint4*)(UT + (size_t)(col4     ) * H_);

    float hnew = 0.0f;
    for (int tl = 0; tl < TC; ++tl) {
        const float* xrow = X + ((size_t)b*TC + tl) * NCOL;
        float acc0 = xrow[tid];
        float acc1 = xrow[256 + tid];
        float acc2 = xrow[512 + tid];
        float acc3 = xrow[768 + tid];
        float acc4 = xrow[col4];

        #pragma unroll 8
        for (int k8 = 0; k8 < 32; ++k8) {
            float4 ha = *(const float4*)&h_s[k8*8];
            float4 hb = *(const float4*)&h_s[k8*8 + 4];
            acc0 = dot8(U0[k8], ha, hb, acc0);
            acc1 = dot8(U1[k8], ha, hb, acc1);
            acc2 = dot8(U2[k8], ha, hb, acc2);
            acc3 = dot8(U3[k8], ha, hb, acc3);
            acc4 = dot8(U4[k8], ha, hb, acc4);
        }
        pre_s[tid]       = acc0;
        pre_s[256 + tid] = acc1;
        pre_s[512 + tid] = acc2;
        pre_s[768 + tid] = acc3;
        if (tid < 16) pre_s[1024 + tid] = acc4;
        __syncthreads();   // SYNC_A: pre_s complete, h_s reads complete

        float x_i   = pre_s[tid];
        float x_ste = pre_s[256 + tid];
        float x_c   = pre_s[528 + tid];
        float x_o   = pre_s[784 + tid];
        float gi   = hsig(x_i);
        float gste = hsig(x_ste);
        float go   = hsig(x_o);
        float cc   = gi * tanhf(x_c);
        int tt = t0 + tl + 1;
        int ttm = tt & 15;
        float Aa = 0.0f;
        int idx = 0;
        #pragma unroll
        for (int f = 0; f < 16; ++f) {
            float fre = hsig(pre_s[512 + f]);
            float dec = gste * fre;
            float sre = fmaf(dec, Sre[f], cc * cs[idx]);
            float sim = fmaf(dec, Sim[f], cc * sn[idx]);
            Sre[f] = sre; Sim[f] = sim;
            Aa = fmaf(fmaf(sre, sre, sim*sim), ua_s[f], Aa);
            idx = (idx + ttm) & 15;
        }
        float a = tanhf(Aa + ba);
        hnew = go * a;
        h_s[tid] = hnew;
        __syncthreads();   // SYNC_B: h_s ready; pre_s reads complete
    }

    // store state back
    h_g[b*H_ + tid] = hnew;
    float4* pr = (float4*)(Sre_g + ((size_t)b*H_ + tid)*16);
    float4* pi = (float4*)(Sim_g + ((size_t)b*H_ + tid)*16);
    #pragma unroll
    for (int q = 0; q < 4; ++q) {
        float4 r, im;
        r.x = Sre[q*4+0]; r.y = Sre[q*4+1]; r.z = Sre[q*4+2]; r.w = Sre[q*4+3];
        im.x = Sim[q*4+0]; im.y = Sim[q*4+1]; im.z = Sim[q*4+2]; im.w = Sim[q*4+3];
        pr[q] = r; pi[q] = im;
    }

    if (t0 + TC == T_) {
        // final head: out[b] = (sum_h h*W_p + b_p) * fc_w + fc_b
        pre_s[tid] = hnew * W_p[tid];
        __syncthreads();
        for (int s = 128; s > 0; s >>= 1) {
            if (tid < s) pre_s[tid] += pre_s[tid + s];
            __syncthreads();
        }
        if (tid == 0) out[b] = (pre_s[0] + b_p[0]) * fc_w[0] + fc_b[0];
    }
}

// ---------------------------------------------------------------------------
extern "C" void kernel_launch(void* const* d_in, const int* in_sizes, int n_in,
                              void* d_out, int out_size, void* d_ws, size_t ws_size,
                              hipStream_t stream) {
    const float* signal = (const float*)d_in[0];
    const float* metmast = (const float*)d_in[1];
    const float* W_i_s   = (const float*)d_in[2];
    const float* W_ste_s = (const float*)d_in[3];
    const float* W_fre_s = (const float*)d_in[4];
    const float* W_c_s   = (const float*)d_in[5];
    const float* W_o_s   = (const float*)d_in[6];
    const float* W_i_m   = (const float*)d_in[7];
    const float* W_ste_m = (const float*)d_in[8];
    const float* W_fre_m = (const float*)d_in[9];
    const float* W_c_m   = (const float*)d_in[10];
    const float* W_o_m   = (const float*)d_in[11];
    const float* U_i   = (const float*)d_in[12];
    const float* b_i   = (const float*)d_in[13];
    const float* U_ste = (const float*)d_in[14];
    const float* b_ste = (const float*)d_in[15];
    const float* U_fre = (const float*)d_in[16];
    const float* b_fre = (const float*)d_in[17];
    const float* U_c   = (const float*)d_in[18];
    const float* b_c   = (const float*)d_in[19];
    const float* U_o   = (const float*)d_in[20];
    const float* b_o   = (const float*)d_in[21];
    const float* U_a   = (const float*)d_in[22];
    const float* b_a   = (const float*)d_in[23];
    const float* W_p   = (const float*)d_in[24];
    const float* b_p   = (const float*)d_in[25];
    const float* fc_w  = (const float*)d_in[26];
    const float* fc_b  = (const float*)d_in[27];
    float* out = (float*)d_out;

    char* ws = (char*)d_ws;
    // byte offsets (all 16B-aligned)
    float*          Wcat = (float*)(ws + 0);                 //  96*1040*4 = 399360
    float*          bcat = (float*)(ws + 399360);            //  1040*4    = 4160
    unsigned short* UT   = (unsigned short*)(ws + 403520);   //  1040*256*2 = 532480
    float*          h_g  = (float*)(ws + 936000);            //  256*256*4 = 262144
    float*          Sre_g= (float*)(ws + 1198144);           //  4194304
    float*          Sim_g= (float*)(ws + 5392448);           //  4194304
    float*          Xch  = (float*)(ws + 9586752);           //  4096*1040*4 = 17039360
    // total 26626112 bytes (~26.6 MB)

    pack_kernel<<<256, 256, 0, stream>>>(
        W_i_s, W_ste_s, W_fre_s, W_c_s, W_o_s,
        W_i_m, W_ste_m, W_fre_m, W_c_m, W_o_m,
        U_i, U_ste, U_fre, U_c, U_o,
        b_i, b_ste, b_fre, b_c, b_o,
        Wcat, bcat, UT);

    for (int chunk = 0; chunk < NCHUNK; ++chunk) {
        int t0 = chunk * TC;
        proj_kernel<<<dim3(9, 32), 256, 0, stream>>>(signal, metmast, Wcat, bcat, Xch, t0);
        recur_kernel<<<B_, 256, 0, stream>>>(Xch, UT, h_g, Sre_g, Sim_g,
                                             U_a, b_a, W_p, b_p, fc_w, fc_b, out, t0);
    }
}